// Round 4
// baseline (344.337 us; speedup 1.0000x reference)
//
#include <hip/hip_runtime.h>
#include <hip/hip_bf16.h>

// Flash-attention fwd, block-causal packed docs. fp32 HBM, bf16 MFMA.
// B=1, H=8, D=128. ONE WAVE PER BLOCK (64 thr), BR=16 q-rows, BC=32 keys.
// Zero barriers: staging + compute same-wave, LDS ordering via lgkmcnt.
// 18.7 KB LDS -> 8 blocks/CU; grid 2048 = 8/CU; heavy tiles dispatch first.
// V staged transposed (key-pair dwords, odd stride 17) -> PV is vector LDS.

#define HD 128
#define BR 16
#define BC 32
#define KSTR 136     // bf16 elems per sK row (128+8): 272 B rows, 16B-aligned, 2-way banks
#define VSTR 17      // DWORDS per sVT row: 16 key-pair dwords + 1 pad (odd -> bank spread)
#define PSTR 40      // bf16 elems per sP row (32+8): 80 B rows, 16B-aligned

typedef __attribute__((ext_vector_type(8))) short short8;
typedef __attribute__((ext_vector_type(4))) short short4v;
typedef __attribute__((ext_vector_type(4))) float floatx4;

__device__ inline unsigned short bfbits(float f) {
    __hip_bfloat16 b = __float2bfloat16(f);
    return *reinterpret_cast<unsigned short*>(&b);
}
__device__ inline short bfs(float f) {
    __hip_bfloat16 b = __float2bfloat16(f);
    return *reinterpret_cast<short*>(&b);
}

__global__ __launch_bounds__(64, 3) void fa_fwd(
    const float* __restrict__ Q,
    const float* __restrict__ K,
    const float* __restrict__ V,
    const int* __restrict__ cu_seqlens, int n_cu,
    float* __restrict__ O,
    int S)
{
    __shared__ alignas(16) __hip_bfloat16 sK[BC * KSTR];     // 8704 B
    __shared__ alignas(16) unsigned int   sVT[HD * VSTR];    // 8704 B  (VT[d][keypair])
    __shared__ alignas(16) __hip_bfloat16 sP[16 * PSTR];     // 1280 B

    const int t    = threadIdx.x;   // 0..63
    const int quad = t >> 4;        // 0..3
    const int l16  = t & 15;
    const int half = t >> 5;        // 0..1 (staging row split)
    const int c4   = t & 31;        // staging float4 column

    const int nqb = S / BR;                     // 256
    const int h   = blockIdx.x & 7;             // head
    const int qb  = nqb - 1 - (int)(blockIdx.x >> 3);  // heavy (long-loop) blocks first
    const int q0  = qb * BR;

    const size_t hoff = (size_t)h * S * HD;
    const float* Qh = Q + hoff;
    const float* Kh = K + hoff;
    const float* Vh = V + hoff;
    float*       Oh = O + hoff;

    // ---- per-row doc starts (C rows: q0 + quad*4 + r) ----
    int doc_start[4];
    #pragma unroll
    for (int r = 0; r < 4; ++r) {
        const int q = q0 + quad * 4 + r;
        int dsr = 0;
        for (int i = 0; i < n_cu; ++i) {
            int c = cu_seqlens[i];
            if (c <= q) dsr = c;
        }
        doc_start[r] = dsr;
    }
    int blk_ds = 0;
    for (int i = 0; i < n_cu; ++i) {
        int c = cu_seqlens[i];
        if (c <= q0) blk_ds = c;
    }
    const int k_begin = blk_ds & ~(BC - 1);
    const int ntiles  = (q0 + BR - 1 - k_begin) / BC + 1;   // wave-uniform

    // ---- Q A-frags: rows q0 + l16, k = ks*32 + quad*8 + j ----
    short8 aq[4];
    {
        const float* qp = Qh + (size_t)(q0 + l16) * HD + quad * 8;
        #pragma unroll
        for (int ks = 0; ks < 4; ++ks) {
            float4 a0 = *(const float4*)(qp + ks * 32);
            float4 a1 = *(const float4*)(qp + ks * 32 + 4);
            short8 a;
            a[0] = bfs(a0.x); a[1] = bfs(a0.y); a[2] = bfs(a0.z); a[3] = bfs(a0.w);
            a[4] = bfs(a1.x); a[5] = bfs(a1.y); a[6] = bfs(a1.z); a[7] = bfs(a1.w);
            aq[ks] = a;
        }
    }

    floatx4 oacc[8];
    #pragma unroll
    for (int dt = 0; dt < 8; ++dt) oacc[dt] = (floatx4){0.f, 0.f, 0.f, 0.f};
    float m_r[4], l_r[4];
    #pragma unroll
    for (int r = 0; r < 4; ++r) { m_r[r] = -1e30f; l_r[r] = 0.f; }

    const float sl = 0.08838834764831845f * 1.4426950408889634f;  // 1/sqrt(128) * log2(e)

    for (int it = 0; it < ntiles; ++it) {
        const int kt = k_begin + it * BC;

        // ---- stage K tile [32 keys x 128 d] -> sK (row-major bf16) ----
        // idx4 = p*64 + t: row = 2p + half, d = 4*c4. 2 full rows per load instr.
        {
            const float* kb = Kh + (size_t)kt * HD + 4 * c4;
            #pragma unroll
            for (int p = 0; p < 16; ++p) {
                const int row = 2 * p + half;
                float4 f = *(const float4*)(kb + (size_t)row * HD);
                short4v hk;
                hk[0] = bfs(f.x); hk[1] = bfs(f.y); hk[2] = bfs(f.z); hk[3] = bfs(f.w);
                *(short4v*)(&sK[row * KSTR + 4 * c4]) = hk;
            }
        }

        // ---- stage V tile transposed -> sVT[d][keypair] dwords ----
        // unit u: keypair rp = 2u + half (keys 2rp, 2rp+1), d = 4*c4 .. +3
        {
            const float* vb = Vh + (size_t)kt * HD + 4 * c4;
            #pragma unroll
            for (int u = 0; u < 8; ++u) {
                const int rp = 2 * u + half;
                const float* v0 = vb + (size_t)(2 * rp) * HD;
                float4 a = *(const float4*)(v0);
                float4 b = *(const float4*)(v0 + HD);
                sVT[(4 * c4 + 0) * VSTR + rp] = ((unsigned)bfbits(b.x) << 16) | bfbits(a.x);
                sVT[(4 * c4 + 1) * VSTR + rp] = ((unsigned)bfbits(b.y) << 16) | bfbits(a.y);
                sVT[(4 * c4 + 2) * VSTR + rp] = ((unsigned)bfbits(b.z) << 16) | bfbits(a.z);
                sVT[(4 * c4 + 3) * VSTR + rp] = ((unsigned)bfbits(b.w) << 16) | bfbits(a.w);
            }
        }
        // no barrier: single wave, in-order DS + compiler lgkmcnt handle RAW/WAR

        // ---- S = Q K^T : 16 q-rows x 32 keys ----
        floatx4 sc[2];
        #pragma unroll
        for (int ct = 0; ct < 2; ++ct) {
            floatx4 c = (floatx4){0.f, 0.f, 0.f, 0.f};
            #pragma unroll
            for (int ks = 0; ks < 4; ++ks) {
                short8 b = *(const short8*)(&sK[(ct * 16 + l16) * KSTR + ks * 32 + quad * 8]);
                c = __builtin_amdgcn_mfma_f32_16x16x32_bf16(aq[ks], b, c, 0, 0, 0);
            }
            sc[ct] = c;
        }

        // ---- scale + mask (C layout: row = quad*4+r, col = ct*16+l16) ----
        #pragma unroll
        for (int ct = 0; ct < 2; ++ct) {
            const int key = kt + ct * 16 + l16;
            #pragma unroll
            for (int r = 0; r < 4; ++r) {
                const int q = q0 + quad * 4 + r;
                const bool valid = (key <= q) && (key >= doc_start[r]);
                float s = sc[ct][r] * sl;
                sc[ct][r] = valid ? s : -1e30f;
            }
        }

        // ---- online softmax (reduce over l16 within quad) ----
        float mx[4];
        #pragma unroll
        for (int r = 0; r < 4; ++r) mx[r] = fmaxf(sc[0][r], sc[1][r]);
        #pragma unroll
        for (int off = 1; off < 16; off <<= 1) {
            #pragma unroll
            for (int r = 0; r < 4; ++r)
                mx[r] = fmaxf(mx[r], __shfl_xor(mx[r], off, 64));
        }
        float al[4];
        #pragma unroll
        for (int r = 0; r < 4; ++r) {
            const float mnew = fmaxf(m_r[r], mx[r]);
            al[r] = exp2f(m_r[r] - mnew);
            m_r[r] = mnew;
        }
        float ps[4];
        #pragma unroll
        for (int r = 0; r < 4; ++r) {
            float s0 = exp2f(sc[0][r] - m_r[r]);   // masked (-1e30) underflows to 0
            float s1 = exp2f(sc[1][r] - m_r[r]);
            sc[0][r] = s0; sc[1][r] = s1;
            ps[r] = s0 + s1;
        }
        #pragma unroll
        for (int off = 1; off < 16; off <<= 1) {
            #pragma unroll
            for (int r = 0; r < 4; ++r)
                ps[r] += __shfl_xor(ps[r], off, 64);
        }
        #pragma unroll
        for (int r = 0; r < 4; ++r)
            l_r[r] = l_r[r] * al[r] + ps[r];
        #pragma unroll
        for (int dt = 0; dt < 8; ++dt) {
            #pragma unroll
            for (int r = 0; r < 4; ++r)
                oacc[dt][r] *= al[r];
        }

        // ---- P: C layout -> sP -> A layout (wave-private) ----
        #pragma unroll
        for (int ct = 0; ct < 2; ++ct)
            #pragma unroll
            for (int r = 0; r < 4; ++r)
                sP[(quad * 4 + r) * PSTR + ct * 16 + l16] = __float2bfloat16(sc[ct][r]);
        short8 ap = *(const short8*)(&sP[l16 * PSTR + quad * 8]);

        // ---- O += P V : B-frag from sVT (keys quad*8..+7 at d = dt*16+l16) ----
        #pragma unroll
        for (int dt = 0; dt < 8; ++dt) {
            const unsigned int* vp = &sVT[(dt * 16 + l16) * VSTR + quad * 4];
            union { unsigned int u[4]; short8 s; } cv;
            cv.u[0] = vp[0]; cv.u[1] = vp[1]; cv.u[2] = vp[2]; cv.u[3] = vp[3];
            oacc[dt] = __builtin_amdgcn_mfma_f32_16x16x32_bf16(ap, cv.s, oacc[dt], 0, 0, 0);
        }
    }

    // ---- epilogue: normalize, store fp32 ----
    #pragma unroll
    for (int r = 0; r < 4; ++r) {
        const float inv = 1.0f / l_r[r];
        float* op = Oh + (size_t)(q0 + quad * 4 + r) * HD;
        #pragma unroll
        for (int dt = 0; dt < 8; ++dt)
            op[dt * 16 + l16] = oacc[dt][r] * inv;
    }
}

extern "C" void kernel_launch(void* const* d_in, const int* in_sizes, int n_in,
                              void* d_out, int out_size, void* d_ws, size_t ws_size,
                              hipStream_t stream) {
    const float* q = (const float*)d_in[0];
    const float* k = (const float*)d_in[1];
    const float* v = (const float*)d_in[2];
    const int* cu = (const int*)d_in[3];
    const int n_cu = in_sizes[3];
    const int H = 8;
    const int S = in_sizes[0] / (H * HD);   // B=1
    float* out = (float*)d_out;

    dim3 grid(H * (S / BR));   // 2048 one-wave blocks
    dim3 block(64);
    fa_fwd<<<grid, block, 0, stream>>>(q, k, v, cu, n_cu, out, S);
}

// Round 6
// 145.716 us; speedup vs baseline: 2.3631x; 2.3631x over previous
//
#include <hip/hip_runtime.h>
#include <hip/hip_bf16.h>

// Flash-attention fwd, block-causal packed docs. fp32 HBM, bf16 MFMA.
// B=1, H=8, D=128. 4 waves/block, BR=64 q-rows, BC=64 keys. Grid 512.
// Software-pipelined staging: tile i+1 global->regs issued during tile i,
// regs->LDS at top of tile i+1. Double-buffered LDS, ONE barrier/tile.
// V^T stored as key-pair dwords (stride 33 dwords) -> write2/read2 access.
// R5 fix: K staging covers all 64 rows (kf[8], was kf[4] -> NaN from
// uninitialized sK rows 32..63).

#define HD 128
#define BR 64
#define BC 64
#define KSTR 136     // bf16 per sK row: 272 B, 16B-aligned
#define VSTR 33      // dwords per sVT row: 32 key-pair dwords + 1 (odd -> spread)
#define PSTR 72      // bf16 per sP row: 144 B, 16B-aligned

typedef __attribute__((ext_vector_type(8))) short short8;
typedef __attribute__((ext_vector_type(4))) short short4v;
typedef __attribute__((ext_vector_type(4))) float floatx4;

__device__ inline unsigned short bfbits(float f) {
    __hip_bfloat16 b = __float2bfloat16(f);
    return *reinterpret_cast<unsigned short*>(&b);
}
__device__ inline short bfs(float f) {
    __hip_bfloat16 b = __float2bfloat16(f);
    return *reinterpret_cast<short*>(&b);
}

union F4 { float4 v; float f[4]; };

__global__ __launch_bounds__(256, 2) void fa_fwd(
    const float* __restrict__ Q,
    const float* __restrict__ K,
    const float* __restrict__ V,
    const int* __restrict__ cu_seqlens, int n_cu,
    float* __restrict__ O,
    int S)
{
    __shared__ alignas(16) __hip_bfloat16 sK[2][BC * KSTR];       // 2 x 17408 B
    __shared__ alignas(16) unsigned int   sVT[2][HD * VSTR];      // 2 x 16896 B
    __shared__ alignas(16) __hip_bfloat16 sP[4][16 * PSTR];       // 9216 B

    const int tid  = threadIdx.x;
    const int wave = tid >> 6;
    const int lane = tid & 63;
    const int quad = lane >> 4;
    const int l16  = lane & 15;

    // staging coords (256 threads)
    const int dblk = tid & 31;      // d = 4*dblk
    const int trow = tid >> 5;      // 0..7

    const int nqb = S / BR;                          // 64
    const int h   = blockIdx.x & 7;
    const int qb  = nqb - 1 - (int)(blockIdx.x >> 3);  // heavy blocks first
    const int q0  = qb * BR;
    const int qw  = q0 + wave * 16;

    const size_t hoff = (size_t)h * S * HD;
    const float* Qh = Q + hoff;
    const float* Kh = K + hoff;
    const float* Vh = V + hoff;
    float*       Oh = O + hoff;

    // ---- per-row doc starts ----
    int doc_start[4];
    #pragma unroll
    for (int r = 0; r < 4; ++r) {
        const int q = qw + quad * 4 + r;
        int dsr = 0;
        for (int i = 0; i < n_cu; ++i) {
            int c = cu_seqlens[i];
            if (c <= q) dsr = c;
        }
        doc_start[r] = dsr;
    }
    int blk_ds = 0;
    for (int i = 0; i < n_cu; ++i) {
        int c = cu_seqlens[i];
        if (c <= q0) blk_ds = c;
    }
    const int k_begin = blk_ds & ~(BC - 1);
    const int ntiles  = (q0 + BR - 1 - k_begin) / BC + 1;   // block-uniform

    // ---- Q A-frags ----
    short8 aq[4];
    {
        const float* qp = Qh + (size_t)(qw + l16) * HD + quad * 8;
        #pragma unroll
        for (int ks = 0; ks < 4; ++ks) {
            float4 a0 = *(const float4*)(qp + ks * 32);
            float4 a1 = *(const float4*)(qp + ks * 32 + 4);
            short8 a;
            a[0] = bfs(a0.x); a[1] = bfs(a0.y); a[2] = bfs(a0.z); a[3] = bfs(a0.w);
            a[4] = bfs(a1.x); a[5] = bfs(a1.y); a[6] = bfs(a1.z); a[7] = bfs(a1.w);
            aq[ks] = a;
        }
    }

    floatx4 oacc[8];
    #pragma unroll
    for (int dt = 0; dt < 8; ++dt) oacc[dt] = (floatx4){0.f, 0.f, 0.f, 0.f};
    float m_r[4], l_r[4];
    #pragma unroll
    for (int r = 0; r < 4; ++r) { m_r[r] = -1e30f; l_r[r] = 0.f; }

    const float sl = 0.08838834764831845f * 1.4426950408889634f;

    // ---- pipeline registers: K 8 x float4 (64 rows), V 8 x float4 ----
    F4 kf[8], vf[2][4];

    auto issue_loads = [&](int kt) {
        const float* kb = Kh + (size_t)kt * HD + 4 * dblk;
        #pragma unroll
        for (int p = 0; p < 8; ++p)
            kf[p].v = *(const float4*)(kb + (size_t)(trow + 8 * p) * HD);
        const float* vb = Vh + (size_t)kt * HD + 4 * dblk;
        #pragma unroll
        for (int p = 0; p < 2; ++p) {
            const int kk = 4 * trow + 32 * p;
            #pragma unroll
            for (int j = 0; j < 4; ++j)
                vf[p][j].v = *(const float4*)(vb + (size_t)(kk + j) * HD);
        }
    };

    auto write_tiles = [&](int buf) {
        // K rows trow+8p (p<8 -> all 64 rows), d = 4*dblk..+3
        #pragma unroll
        for (int p = 0; p < 8; ++p) {
            short4v hk;
            hk[0] = bfs(kf[p].f[0]); hk[1] = bfs(kf[p].f[1]);
            hk[2] = bfs(kf[p].f[2]); hk[3] = bfs(kf[p].f[3]);
            *(short4v*)(&sK[buf][(trow + 8 * p) * KSTR + 4 * dblk]) = hk;
        }
        // V^T: keys kk..kk+3 at d = 4*dblk+i -> 2 adjacent dwords per (p,i)
        #pragma unroll
        for (int p = 0; p < 2; ++p) {
            const int kp0 = (4 * trow + 32 * p) >> 1;   // key-pair index
            #pragma unroll
            for (int i = 0; i < 4; ++i) {
                unsigned d0 = ((unsigned)bfbits(vf[p][1].f[i]) << 16) | bfbits(vf[p][0].f[i]);
                unsigned d1 = ((unsigned)bfbits(vf[p][3].f[i]) << 16) | bfbits(vf[p][2].f[i]);
                unsigned* dst = &sVT[buf][(4 * dblk + i) * VSTR + kp0];
                dst[0] = d0;
                dst[1] = d1;
            }
        }
    };

    issue_loads(k_begin);   // preload tile 0

    __hip_bfloat16* pbuf = &sP[wave][0];

    for (int it = 0; it < ntiles; ++it) {
        const int kt  = k_begin + it * BC;
        const int buf = it & 1;

        // (a) drain prefetch regs -> LDS[buf]
        write_tiles(buf);
        __syncthreads();

        // (b) issue next tile's global loads (overlap with compute below)
        if (it + 1 < ntiles) issue_loads(kt + BC);

        // (c) S = Q K^T : 16 q-rows x 64 keys
        floatx4 sc[4];
        #pragma unroll
        for (int ct = 0; ct < 4; ++ct) {
            floatx4 c = (floatx4){0.f, 0.f, 0.f, 0.f};
            #pragma unroll
            for (int ks = 0; ks < 4; ++ks) {
                short8 b = *(const short8*)(&sK[buf][(ct * 16 + l16) * KSTR + ks * 32 + quad * 8]);
                c = __builtin_amdgcn_mfma_f32_16x16x32_bf16(aq[ks], b, c, 0, 0, 0);
            }
            sc[ct] = c;
        }

        // scale + mask (C layout: row = quad*4+r, col = ct*16+l16)
        #pragma unroll
        for (int ct = 0; ct < 4; ++ct) {
            const int key = kt + ct * 16 + l16;
            #pragma unroll
            for (int r = 0; r < 4; ++r) {
                const int q = qw + quad * 4 + r;
                const bool valid = (key <= q) && (key >= doc_start[r]);
                float s = sc[ct][r] * sl;
                sc[ct][r] = valid ? s : -1e30f;
            }
        }

        // online softmax
        float mx[4];
        #pragma unroll
        for (int r = 0; r < 4; ++r)
            mx[r] = fmaxf(fmaxf(sc[0][r], sc[1][r]), fmaxf(sc[2][r], sc[3][r]));
        #pragma unroll
        for (int off = 1; off < 16; off <<= 1) {
            #pragma unroll
            for (int r = 0; r < 4; ++r)
                mx[r] = fmaxf(mx[r], __shfl_xor(mx[r], off, 64));
        }
        float al[4];
        #pragma unroll
        for (int r = 0; r < 4; ++r) {
            const float mnew = fmaxf(m_r[r], mx[r]);
            al[r] = exp2f(m_r[r] - mnew);
            m_r[r] = mnew;
        }
        float ps[4];
        #pragma unroll
        for (int r = 0; r < 4; ++r) {
            float s0 = exp2f(sc[0][r] - m_r[r]);
            float s1 = exp2f(sc[1][r] - m_r[r]);
            float s2 = exp2f(sc[2][r] - m_r[r]);
            float s3 = exp2f(sc[3][r] - m_r[r]);
            sc[0][r] = s0; sc[1][r] = s1; sc[2][r] = s2; sc[3][r] = s3;
            ps[r] = (s0 + s1) + (s2 + s3);
        }
        #pragma unroll
        for (int off = 1; off < 16; off <<= 1) {
            #pragma unroll
            for (int r = 0; r < 4; ++r)
                ps[r] += __shfl_xor(ps[r], off, 64);
        }
        #pragma unroll
        for (int r = 0; r < 4; ++r)
            l_r[r] = l_r[r] * al[r] + ps[r];
        #pragma unroll
        for (int dt = 0; dt < 8; ++dt) {
            #pragma unroll
            for (int r = 0; r < 4; ++r)
                oacc[dt][r] *= al[r];
        }

        // P: C layout -> wave-private LDS -> A layout
        #pragma unroll
        for (int ct = 0; ct < 4; ++ct)
            #pragma unroll
            for (int r = 0; r < 4; ++r)
                pbuf[(quad * 4 + r) * PSTR + ct * 16 + l16] = __float2bfloat16(sc[ct][r]);

        // O += P V  (B-frag: 4 consecutive dwords of sVT)
        #pragma unroll
        for (int ks = 0; ks < 2; ++ks) {
            short8 ap = *(const short8*)(&pbuf[l16 * PSTR + ks * 32 + quad * 8]);
            #pragma unroll
            for (int dt = 0; dt < 8; ++dt) {
                const unsigned* vp = &sVT[buf][(dt * 16 + l16) * VSTR + ks * 16 + quad * 4];
                union { unsigned u[4]; short8 s; } cv;
                cv.u[0] = vp[0]; cv.u[1] = vp[1]; cv.u[2] = vp[2]; cv.u[3] = vp[3];
                oacc[dt] = __builtin_amdgcn_mfma_f32_16x16x32_bf16(ap, cv.s, oacc[dt], 0, 0, 0);
            }
        }
    }

    // ---- epilogue ----
    #pragma unroll
    for (int r = 0; r < 4; ++r) {
        const float inv = 1.0f / l_r[r];
        float* op = Oh + (size_t)(qw + quad * 4 + r) * HD;
        #pragma unroll
        for (int dt = 0; dt < 8; ++dt)
            op[dt * 16 + l16] = oacc[dt][r] * inv;
    }
}

extern "C" void kernel_launch(void* const* d_in, const int* in_sizes, int n_in,
                              void* d_out, int out_size, void* d_ws, size_t ws_size,
                              hipStream_t stream) {
    const float* q = (const float*)d_in[0];
    const float* k = (const float*)d_in[1];
    const float* v = (const float*)d_in[2];
    const int* cu = (const int*)d_in[3];
    const int n_cu = in_sizes[3];
    const int H = 8;
    const int S = in_sizes[0] / (H * HD);   // B=1
    float* out = (float*)d_out;

    dim3 grid(H * (S / BR));   // 512 blocks
    dim3 block(256);
    fa_fwd<<<grid, block, 0, stream>>>(q, k, v, cu, n_cu, out, S);
}

// Round 7
// 141.591 us; speedup vs baseline: 2.4319x; 1.0291x over previous
//
#include <hip/hip_runtime.h>
#include <hip/hip_bf16.h>

// Flash-attention fwd, block-causal packed docs. fp32 HBM, bf16 MFMA.
// B=1, H=8, D=128. 4 waves/block, BR=64, BC=64, grid 512, 2 blocks/CU.
// Register-prefetch pipeline (R5), double-buffered LDS, 1 barrier/tile.
// R6: per-lane deferred l-sum; V^T staged one-d-per-lane (2-way banks);
// sP stride 68; wave-uniform causal block-skip on diagonal tiles.

#define HD 128
#define BR 64
#define BC 64
#define KSTR 136     // bf16 per sK row: 272 B
#define VSTR 33      // dwords per sVT row (32 key-pair dwords + 1 pad; odd)
#define PSTR 68      // bf16 per sP row: 136 B (write banks ~2-way)

typedef __attribute__((ext_vector_type(8))) short short8;
typedef __attribute__((ext_vector_type(4))) short short4v;
typedef __attribute__((ext_vector_type(4))) float floatx4;

__device__ inline unsigned short bfbits(float f) {
    __hip_bfloat16 b = __float2bfloat16(f);
    return *reinterpret_cast<unsigned short*>(&b);
}
__device__ inline short bfs(float f) {
    __hip_bfloat16 b = __float2bfloat16(f);
    return *reinterpret_cast<short*>(&b);
}

union F4 { float4 v; float f[4]; };

__global__ __launch_bounds__(256, 2) void fa_fwd(
    const float* __restrict__ Q,
    const float* __restrict__ K,
    const float* __restrict__ V,
    const int* __restrict__ cu_seqlens, int n_cu,
    float* __restrict__ O,
    int S)
{
    __shared__ alignas(16) __hip_bfloat16 sK[2][BC * KSTR];   // 34816 B
    __shared__ alignas(16) unsigned int   sVT[2][HD * VSTR];  // 33792 B
    __shared__ alignas(16) __hip_bfloat16 sP[4][16 * PSTR];   // 8704 B

    const int tid  = threadIdx.x;
    const int wave = tid >> 6;
    const int lane = tid & 63;
    const int quad = lane >> 4;
    const int l16  = lane & 15;

    // K staging coords
    const int dblk = tid & 31;      // d = 4*dblk
    const int trow = tid >> 5;      // 0..7
    // V staging coords: one d-row per thread
    const int vd    = tid & 127;    // d row
    const int vhalf = tid >> 7;     // key half (0..1)

    const int nqb = S / BR;
    const int h   = blockIdx.x & 7;
    const int qb  = nqb - 1 - (int)(blockIdx.x >> 3);  // heavy blocks first
    const int q0  = qb * BR;
    const int qw  = q0 + wave * 16;

    const size_t hoff = (size_t)h * S * HD;
    const float* Qh = Q + hoff;
    const float* Kh = K + hoff;
    const float* Vh = V + hoff;
    float*       Oh = O + hoff;

    // ---- per-row doc starts ----
    int doc_start[4];
    #pragma unroll
    for (int r = 0; r < 4; ++r) {
        const int q = qw + quad * 4 + r;
        int dsr = 0;
        for (int i = 0; i < n_cu; ++i) {
            int c = cu_seqlens[i];
            if (c <= q) dsr = c;
        }
        doc_start[r] = dsr;
    }
    int blk_ds = 0;
    for (int i = 0; i < n_cu; ++i) {
        int c = cu_seqlens[i];
        if (c <= q0) blk_ds = c;
    }
    const int k_begin = blk_ds & ~(BC - 1);
    const int ntiles  = (q0 + BR - 1 - k_begin) / BC + 1;   // block-uniform

    // ---- Q A-frags ----
    short8 aq[4];
    {
        const float* qp = Qh + (size_t)(qw + l16) * HD + quad * 8;
        #pragma unroll
        for (int ks = 0; ks < 4; ++ks) {
            float4 a0 = *(const float4*)(qp + ks * 32);
            float4 a1 = *(const float4*)(qp + ks * 32 + 4);
            short8 a;
            a[0] = bfs(a0.x); a[1] = bfs(a0.y); a[2] = bfs(a0.z); a[3] = bfs(a0.w);
            a[4] = bfs(a1.x); a[5] = bfs(a1.y); a[6] = bfs(a1.z); a[7] = bfs(a1.w);
            aq[ks] = a;
        }
    }

    floatx4 oacc[8];
    #pragma unroll
    for (int dt = 0; dt < 8; ++dt) oacc[dt] = (floatx4){0.f, 0.f, 0.f, 0.f};
    float m_r[4], l_r[4];   // l_r: PER-LANE partial row sums (reduced at end)
    #pragma unroll
    for (int r = 0; r < 4; ++r) { m_r[r] = -1e30f; l_r[r] = 0.f; }

    const float sl = 0.08838834764831845f * 1.4426950408889634f;

    // ---- pipeline registers ----
    F4 kf[8];
    float vf[32];

    auto issue_loads = [&](int kt) {
        const float* kb = Kh + (size_t)kt * HD + 4 * dblk;
        #pragma unroll
        for (int p = 0; p < 8; ++p)
            kf[p].v = *(const float4*)(kb + (size_t)(trow + 8 * p) * HD);
        const float* vb = Vh + (size_t)(kt + vhalf * 32) * HD + vd;
        #pragma unroll
        for (int kk = 0; kk < 32; ++kk)
            vf[kk] = vb[(size_t)kk * HD];
    };

    auto write_tiles = [&](int buf) {
        #pragma unroll
        for (int p = 0; p < 8; ++p) {
            short4v hk;
            hk[0] = bfs(kf[p].f[0]); hk[1] = bfs(kf[p].f[1]);
            hk[2] = bfs(kf[p].f[2]); hk[3] = bfs(kf[p].f[3]);
            *(short4v*)(&sK[buf][(trow + 8 * p) * KSTR + 4 * dblk]) = hk;
        }
        // V^T: this thread owns d-row vd, key-pairs vhalf*16 .. +15
        unsigned* dst = &sVT[buf][vd * VSTR + vhalf * 16];
        #pragma unroll
        for (int kp = 0; kp < 16; ++kp)
            dst[kp] = ((unsigned)bfbits(vf[2 * kp + 1]) << 16) | bfbits(vf[2 * kp]);
    };

    issue_loads(k_begin);

    __hip_bfloat16* pbuf = &sP[wave][0];

    for (int it = 0; it < ntiles; ++it) {
        const int kt  = k_begin + it * BC;
        const int buf = it & 1;

        write_tiles(buf);
        __syncthreads();

        if (it + 1 < ntiles) issue_loads(kt + BC);

        // ---- S = Q K^T (skip fully-causal-masked 16-key blocks) ----
        floatx4 sc[4];
        #pragma unroll
        for (int ct = 0; ct < 4; ++ct) {
            if (kt + ct * 16 <= qw + 15) {          // wave-uniform
                floatx4 c = (floatx4){0.f, 0.f, 0.f, 0.f};
                #pragma unroll
                for (int ks = 0; ks < 4; ++ks) {
                    short8 b = *(const short8*)(&sK[buf][(ct * 16 + l16) * KSTR + ks * 32 + quad * 8]);
                    c = __builtin_amdgcn_mfma_f32_16x16x32_bf16(aq[ks], b, c, 0, 0, 0);
                }
                const int key = kt + ct * 16 + l16;
                #pragma unroll
                for (int r = 0; r < 4; ++r) {
                    const int q = qw + quad * 4 + r;
                    const bool valid = (key <= q) && (key >= doc_start[r]);
                    float s = c[r] * sl;
                    c[r] = valid ? s : -1e30f;
                }
                sc[ct] = c;
            } else {
                sc[ct] = (floatx4){-1e30f, -1e30f, -1e30f, -1e30f};
            }
        }

        // ---- online softmax: max-reduce only; l kept per-lane ----
        float mx[4];
        #pragma unroll
        for (int r = 0; r < 4; ++r)
            mx[r] = fmaxf(fmaxf(sc[0][r], sc[1][r]), fmaxf(sc[2][r], sc[3][r]));
        #pragma unroll
        for (int off = 1; off < 16; off <<= 1) {
            #pragma unroll
            for (int r = 0; r < 4; ++r)
                mx[r] = fmaxf(mx[r], __shfl_xor(mx[r], off, 64));
        }
        float al[4];
        #pragma unroll
        for (int r = 0; r < 4; ++r) {
            const float mnew = fmaxf(m_r[r], mx[r]);
            al[r] = exp2f(m_r[r] - mnew);
            m_r[r] = mnew;
        }
        #pragma unroll
        for (int r = 0; r < 4; ++r) {
            float s0 = exp2f(sc[0][r] - m_r[r]);
            float s1 = exp2f(sc[1][r] - m_r[r]);
            float s2 = exp2f(sc[2][r] - m_r[r]);
            float s3 = exp2f(sc[3][r] - m_r[r]);
            sc[0][r] = s0; sc[1][r] = s1; sc[2][r] = s2; sc[3][r] = s3;
            l_r[r] = l_r[r] * al[r] + ((s0 + s1) + (s2 + s3));   // per-lane partial
        }
        #pragma unroll
        for (int dt = 0; dt < 8; ++dt) {
            #pragma unroll
            for (int r = 0; r < 4; ++r)
                oacc[dt][r] *= al[r];
        }

        // ---- P: C layout -> wave-private LDS -> A layout ----
        #pragma unroll
        for (int ct = 0; ct < 4; ++ct)
            #pragma unroll
            for (int r = 0; r < 4; ++r)
                pbuf[(quad * 4 + r) * PSTR + ct * 16 + l16] = __float2bfloat16(sc[ct][r]);

        // ---- O += P V (skip fully-masked 32-key halves) ----
        #pragma unroll
        for (int ks = 0; ks < 2; ++ks) {
            if (kt + ks * 32 <= qw + 15) {          // wave-uniform
                short4v lo = *(const short4v*)(&pbuf[l16 * PSTR + ks * 32 + quad * 8]);
                short4v hi = *(const short4v*)(&pbuf[l16 * PSTR + ks * 32 + quad * 8 + 4]);
                short8 ap = __builtin_shufflevector(lo, hi, 0, 1, 2, 3, 4, 5, 6, 7);
                #pragma unroll
                for (int dt = 0; dt < 8; ++dt) {
                    const unsigned* vp = &sVT[buf][(dt * 16 + l16) * VSTR + ks * 16 + quad * 4];
                    union { unsigned u[4]; short8 s; } cv;
                    cv.u[0] = vp[0]; cv.u[1] = vp[1]; cv.u[2] = vp[2]; cv.u[3] = vp[3];
                    oacc[dt] = __builtin_amdgcn_mfma_f32_16x16x32_bf16(ap, cv.s, oacc[dt], 0, 0, 0);
                }
            }
        }
    }

    // ---- epilogue: reduce l across the 16 lanes of each row, store ----
    #pragma unroll
    for (int off = 1; off < 16; off <<= 1) {
        #pragma unroll
        for (int r = 0; r < 4; ++r)
            l_r[r] += __shfl_xor(l_r[r], off, 64);
    }
    #pragma unroll
    for (int r = 0; r < 4; ++r) {
        const float inv = 1.0f / l_r[r];
        float* op = Oh + (size_t)(qw + quad * 4 + r) * HD;
        #pragma unroll
        for (int dt = 0; dt < 8; ++dt)
            op[dt * 16 + l16] = oacc[dt][r] * inv;
    }
}

extern "C" void kernel_launch(void* const* d_in, const int* in_sizes, int n_in,
                              void* d_out, int out_size, void* d_ws, size_t ws_size,
                              hipStream_t stream) {
    const float* q = (const float*)d_in[0];
    const float* k = (const float*)d_in[1];
    const float* v = (const float*)d_in[2];
    const int* cu = (const int*)d_in[3];
    const int n_cu = in_sizes[3];
    const int H = 8;
    const int S = in_sizes[0] / (H * HD);   // B=1
    float* out = (float*)d_out;

    dim3 grid(H * (S / BR));   // 512 blocks
    dim3 block(256);
    fa_fwd<<<grid, block, 0, stream>>>(q, k, v, cu, n_cu, out, S);
}